// Round 1
// baseline (226.829 us; speedup 1.0000x reference)
//
#include <hip/hip_runtime.h>
#include <math.h>

#define S_LEN 2048
#define D_DIM 128
#define BHN   32
#define NKT   32   // KV tiles of 64
#define NQT   32   // Q tiles of 64

typedef _Float16 f16;
typedef __attribute__((ext_vector_type(4))) _Float16 f16x4;
typedef __attribute__((ext_vector_type(8))) _Float16 f16x8;
typedef __attribute__((ext_vector_type(4))) float    f32x4;

__device__ __forceinline__ void async_cp16(const void* g, void* l) {
  __builtin_amdgcn_global_load_lds(
      (const __attribute__((address_space(1))) unsigned int*)g,
      (__attribute__((address_space(3))) unsigned int*)l,
      16, 0, 0);
}

// ---- prepass A: K fp32 [bh][s][d] -> ws fp16 tiles [bh][jt][r(64)][chunk'(16)][8]
// chunk' = kd ^ (r & 15)  (XOR swizzle so mfma B-frag ds_read_b128 is bank-balanced)
__global__ __launch_bounds__(256) void convert_k_kernel(const float* __restrict__ k,
                                                        f16* __restrict__ kw) {
  int g  = blockIdx.x * 256 + threadIdx.x;   // 16B-chunk id, 0..1048575
  int kd = g & 15;
  int s  = (g >> 4) & (S_LEN - 1);
  int bh = g >> 15;
  const float* src = k + (((size_t)bh * S_LEN + s) * D_DIM + kd * 8);
  float4 a = *(const float4*)src;
  float4 b = *(const float4*)(src + 4);
  int r  = s & 63;
  int jt = s >> 6;
  f16x8 vv;
  vv[0]=(f16)a.x; vv[1]=(f16)a.y; vv[2]=(f16)a.z; vv[3]=(f16)a.w;
  vv[4]=(f16)b.x; vv[5]=(f16)b.y; vv[6]=(f16)b.z; vv[7]=(f16)b.w;
  f16* dst = kw + ((((size_t)bh * NKT + jt) * 64 + r) * D_DIM + ((kd ^ (r & 15)) * 8));
  *(f16x8*)dst = vv;
}

// ---- prepass B: V fp32 [bh][s][d] -> ws fp16 transposed tiles [bh][jt][d(128)][chunk'(8)][8]
// chunk' = kc ^ (d & 7)
__global__ __launch_bounds__(256) void transpose_v_kernel(const float* __restrict__ v,
                                                          f16* __restrict__ vtw) {
  int bh = blockIdx.x >> 5;
  int jt = blockIdx.x & 31;
  int t  = threadIdx.x;
  int rq = t >> 4;   // kv quad: rows rq*4..rq*4+3 of the 64-row tile
  int dg = t & 15;   // d octet (coalesced global reads across lanes)
  const float* base = v + (((size_t)bh * S_LEN + jt * 64 + rq * 4) * D_DIM + dg * 8);
  float rows[4][8];
#pragma unroll
  for (int rr = 0; rr < 4; ++rr) {
    float4 aa = *(const float4*)(base + rr * D_DIM);
    float4 bb = *(const float4*)(base + rr * D_DIM + 4);
    rows[rr][0]=aa.x; rows[rr][1]=aa.y; rows[rr][2]=aa.z; rows[rr][3]=aa.w;
    rows[rr][4]=bb.x; rows[rr][5]=bb.y; rows[rr][6]=bb.z; rows[rr][7]=bb.w;
  }
  f16* tbase = vtw + ((size_t)bh * NKT + jt) * (D_DIM * 64);
  int kc = rq >> 1;
  int kk = (rq & 1) * 4;
#pragma unroll
  for (int dd = 0; dd < 8; ++dd) {
    int d = dg * 8 + dd;
    f16x4 p;
    p[0]=(f16)rows[0][dd]; p[1]=(f16)rows[1][dd];
    p[2]=(f16)rows[2][dd]; p[3]=(f16)rows[3][dd];
    *(f16x4*)(tbase + d * 64 + ((kc ^ (d & 7)) * 8) + kk) = p;
  }
}

// ---- main: flash attention, fp16 MFMA 16x16x32, online softmax
// block = 256 thr (4 waves), Q-tile = 64 rows (16/wave), KV-tile = 64
__global__ __launch_bounds__(256) void attn_kernel(const float* __restrict__ q,
                                                   const f16* __restrict__ kw,
                                                   const f16* __restrict__ vtw,
                                                   const float* __restrict__ am,
                                                   const float* __restrict__ hm,
                                                   float* __restrict__ out) {
  __shared__ f16 Klds[64 * 128];   // 16 KB, swizzled image of K tile
  __shared__ f16 Vlds[128 * 64];   // 16 KB, swizzled image of V^T tile
  __shared__ f16 Plds[64 * 68];    // P round-trip; stride 68 -> conflict-free b16 writes

  const int bx   = blockIdx.x;
  const int bh   = bx & 31;
  const int qi   = (NQT - 1) - (bx >> 5);   // heaviest (longest causal span) first
  const int b    = bh >> 4;
  const int h    = bh & 15;
  const int t    = threadIdx.x;
  const int w    = t >> 6;
  const int lane = t & 63;
  const int c    = lane & 15;
  const int quad = lane >> 4;
  const int qb   = qi * 64;

  // Q fragments, A-layout: A[m=lane&15][k=quad*8+j]; row = qb + w*16 + c
  f16x8 qf[4];
  {
    const float* qsrc = q + (((size_t)bh * S_LEN + qb + w * 16 + c) * D_DIM + quad * 8);
#pragma unroll
    for (int ks = 0; ks < 4; ++ks) {
      float4 a  = *(const float4*)(qsrc + ks * 32);
      float4 bb = *(const float4*)(qsrc + ks * 32 + 4);
      f16x8 vv;
      vv[0]=(f16)a.x;  vv[1]=(f16)a.y;  vv[2]=(f16)a.z;  vv[3]=(f16)a.w;
      vv[4]=(f16)bb.x; vv[5]=(f16)bb.y; vv[6]=(f16)bb.z; vv[7]=(f16)bb.w;
      qf[ks] = vv;
    }
  }

  const float hmv  = hm[h];
  const float* amp = am + (size_t)b * S_LEN;

  f32x4 zero4; zero4[0]=0.f; zero4[1]=0.f; zero4[2]=0.f; zero4[3]=0.f;
  f32x4 oacc[8];
#pragma unroll
  for (int dt = 0; dt < 8; ++dt) oacc[dt] = zero4;
  float mrow[4] = {-INFINITY, -INFINITY, -INFINITY, -INFINITY};
  float lrow[4] = {0.f, 0.f, 0.f, 0.f};

  const size_t ktile0 = (size_t)bh * NKT * (64 * 128);
  const size_t vtile0 = (size_t)bh * NKT * (128 * 64);

  for (int j = 0; j <= qi; ++j) {
    __syncthreads();   // all waves done reading previous tile
    {
      const f16* kg = kw  + ktile0 + (size_t)j * (64 * 128) + (w * 4) * 512 + lane * 8;
      const f16* vg = vtw + vtile0 + (size_t)j * (128 * 64) + (w * 4) * 512 + lane * 8;
      f16* kl = Klds + (w * 4) * 512;
      f16* vl = Vlds + (w * 4) * 512;
#pragma unroll
      for (int i = 0; i < 4; ++i) async_cp16(kg + i * 512, kl + i * 512);
#pragma unroll
      for (int i = 0; i < 4; ++i) async_cp16(vg + i * 512, vl + i * 512);
    }
    __syncthreads();   // drains vmcnt -> tiles resident

    float amv[4];
#pragma unroll
    for (int nt = 0; nt < 4; ++nt) amv[nt] = amp[j * 64 + nt * 16 + c];

    // S = Q K^T  (B-frag: B[k][n]=K[n][k], n=lane&15 -> K-tile row c)
    f32x4 sacc[4];
#pragma unroll
    for (int nt = 0; nt < 4; ++nt) sacc[nt] = zero4;
#pragma unroll
    for (int ks = 0; ks < 4; ++ks) {
#pragma unroll
      for (int nt = 0; nt < 4; ++nt) {
        const f16x8* bf = (const f16x8*)(Klds + (nt * 16 + c) * 128 + (((ks * 4 + quad) ^ c) * 8));
        sacc[nt] = __builtin_amdgcn_mfma_f32_16x16x32_f16(qf[ks], *bf, sacc[nt], 0, 0, 0);
      }
    }

    // causal mask only on the diagonal tile (wave-uniform branch)
    if (j == qi) {
#pragma unroll
      for (int nt = 0; nt < 4; ++nt)
#pragma unroll
        for (int r = 0; r < 4; ++r) {
          int col  = j * 64 + nt * 16 + c;
          int rowv = qb + w * 16 + quad * 4 + r;
          if (col > rowv) sacc[nt][r] = -INFINITY;
        }
    }
#pragma unroll
    for (int nt = 0; nt < 4; ++nt)
#pragma unroll
      for (int r = 0; r < 4; ++r) sacc[nt][r] += amv[nt];

    // online softmax: rows owned = quad*4 + r; reduce over the 16 lanes of the quad
    float al4[4];
#pragma unroll
    for (int r = 0; r < 4; ++r) {
      float tm = fmaxf(fmaxf(sacc[0][r], sacc[1][r]), fmaxf(sacc[2][r], sacc[3][r]));
      tm = fmaxf(tm, __shfl_xor(tm, 1));
      tm = fmaxf(tm, __shfl_xor(tm, 2));
      tm = fmaxf(tm, __shfl_xor(tm, 4));
      tm = fmaxf(tm, __shfl_xor(tm, 8));
      float mnew = fmaxf(mrow[r], tm);
      al4[r] = __expf(mrow[r] - mnew);
      mrow[r] = mnew;
#pragma unroll
      for (int nt = 0; nt < 4; ++nt) sacc[nt][r] = __expf(sacc[nt][r] - mnew);
      float s4 = sacc[0][r] + sacc[1][r] + sacc[2][r] + sacc[3][r];
      s4 += __shfl_xor(s4, 1);
      s4 += __shfl_xor(s4, 2);
      s4 += __shfl_xor(s4, 4);
      s4 += __shfl_xor(s4, 8);
      lrow[r] = lrow[r] * al4[r] + s4;
    }

    // P: C-layout -> LDS -> A-layout (own 16-row strip only; no barrier needed)
#pragma unroll
    for (int nt = 0; nt < 4; ++nt)
#pragma unroll
      for (int r = 0; r < 4; ++r)
        Plds[(w * 16 + quad * 4 + r) * 68 + nt * 16 + c] = (f16)sacc[nt][r];

    f32x4 alv; alv[0]=al4[0]; alv[1]=al4[1]; alv[2]=al4[2]; alv[3]=al4[3];
#pragma unroll
    for (int dt = 0; dt < 8; ++dt) oacc[dt] *= alv;

    // O += P V  (A = P strip, B-frag from swizzled V^T image)
#pragma unroll
    for (int ks2 = 0; ks2 < 2; ++ks2) {
      const f16* pb = Plds + (w * 16 + c) * 68 + ks2 * 32 + quad * 8;
      f16x4 a0 = *(const f16x4*)(pb);
      f16x4 a1 = *(const f16x4*)(pb + 4);
      f16x8 af;
#pragma unroll
      for (int jj = 0; jj < 4; ++jj) { af[jj] = a0[jj]; af[jj + 4] = a1[jj]; }
#pragma unroll
      for (int dt = 0; dt < 8; ++dt) {
        const f16x8* bf = (const f16x8*)(Vlds + (dt * 16 + c) * 64 + (((ks2 * 4 + quad) ^ (c & 7)) * 8));
        oacc[dt] = __builtin_amdgcn_mfma_f32_16x16x32_f16(af, *bf, oacc[dt], 0, 0, 0);
      }
    }
  }

  // epilogue: out = head_mask * O / l
  float rinv[4];
#pragma unroll
  for (int r = 0; r < 4; ++r) rinv[r] = hmv / lrow[r];
  float* obase = out + (((size_t)bh * S_LEN + qb + w * 16) * D_DIM);
#pragma unroll
  for (int dt = 0; dt < 8; ++dt)
#pragma unroll
    for (int r = 0; r < 4; ++r)
      obase[(quad * 4 + r) * D_DIM + dt * 16 + c] = oacc[dt][r] * rinv[r];
}

extern "C" void kernel_launch(void* const* d_in, const int* in_sizes, int n_in,
                              void* d_out, int out_size, void* d_ws, size_t ws_size,
                              hipStream_t stream) {
  const float* q  = (const float*)d_in[0];
  const float* k  = (const float*)d_in[1];
  const float* v  = (const float*)d_in[2];
  const float* am = (const float*)d_in[3];
  const float* hm = (const float*)d_in[4];
  float* out = (float*)d_out;

  f16* kw  = (f16*)d_ws;                              // 16.78 MB
  f16* vtw = kw + (size_t)BHN * S_LEN * D_DIM;        // 16.78 MB

  convert_k_kernel<<<4096, 256, 0, stream>>>(k, kw);
  transpose_v_kernel<<<1024, 256, 0, stream>>>(v, vtw);
  attn_kernel<<<1024, 256, 0, stream>>>(q, kw, vtw, am, hm, out);
}